// Round 4
// baseline (1539.756 us; speedup 1.0000x reference)
//
#include <hip/hip_runtime.h>

#define NNODES 100000
#define NEDGES 1600000

// ---------- bf16 helpers ----------
__device__ __forceinline__ float bf2f(unsigned v) {
  union { unsigned u; float f; } x; x.u = v << 16; return x.f;
}
__device__ __forceinline__ unsigned short f2bf(float f) {
  union { float f; unsigned u; } x; x.f = f;
  unsigned r = x.u + 0x7fffu + ((x.u >> 16) & 1u);
  return (unsigned short)(r >> 16);
}

// ---------- dtype probing ----------
// flags[0] = 1 if float inputs are fp32 (else bf16)
// flags[1] = 1 if edge_index is int64 (else int32)
__global__ void k_probe(const unsigned* __restrict__ xw, const int* __restrict__ ei,
                        int* __restrict__ flags) {
  __shared__ int cF, cI;
  if (threadIdx.x == 0) { cF = 0; cI = 0; }
  __syncthreads();
  int t = threadIdx.x;
  int hf = 0;
  for (int i = t; i < 2048; i += 256) {
    unsigned lo = xw[i] & 0xffffu;
    unsigned e = (lo >> 7) & 0xffu;   // exponent field of low-half bf16
    if (e >= 0xC0u) hf++;             // |val| >= 2^65: impossible for N(0,1) bf16
  }
  atomicAdd(&cF, hf);
  int hi = 0;
  if (ei[2 * t + 1] != 0) hi++;       // high words of int64 would all be 0
  atomicAdd(&cI, hi);
  __syncthreads();
  if (threadIdx.x == 0) {
    flags[0] = (cF > 32) ? 1 : 0;
    flags[1] = (cI < 16) ? 1 : 0;
  }
}

// sentinel prefill of the fp32 output: decodes flags if pipeline dies later
__global__ void k_sentinel(float* __restrict__ out, const int* __restrict__ flags,
                           int ok) {
  float v = 16.f + 8.f * flags[0] + 4.f * flags[1] + 2.f * ok;
  for (long long i = (long long)blockIdx.x * 256 + threadIdx.x; i < 16000000LL;
       i += (long long)gridDim.x * 256)
    out[i] = v;
}

__device__ __forceinline__ int edge_at(const int* __restrict__ ei, int j, int i64) {
  return i64 ? ei[2 * j] : ei[j];
}

// ---------- canonicalize float arrays to bf16 ----------
struct CvtParams {
  const void* src[13];
  unsigned short* dst[13];
  int n[13];
};

__global__ void k_cvt(CvtParams p, const int* __restrict__ flags) {
  int a = blockIdx.y;
  int n = p.n[a];
  int f32 = flags[0];
  const float* sf = (const float*)p.src[a];
  const unsigned short* sb = (const unsigned short*)p.src[a];
  unsigned short* d = p.dst[a];
  for (int i = blockIdx.x * blockDim.x + threadIdx.x; i < n; i += gridDim.x * blockDim.x) {
    d[i] = f32 ? f2bf(sf[i]) : sb[i];
  }
}

__global__ void k_zero(int* __restrict__ p, int n) {
  int v = blockIdx.x * blockDim.x + threadIdx.x;
  if (v < n) p[v] = 0;
}

// ---------- graph preprocessing ----------
__global__ void k_count(const int* __restrict__ ei, int* __restrict__ cnt,
                        const int* __restrict__ flags) {
  int e = blockIdx.x * blockDim.x + threadIdx.x;
  if (e < NEDGES) {
    int i64 = flags[1];
    int d = edge_at(ei, NEDGES + e, i64);
    if ((unsigned)d < NNODES) atomicAdd(&cnt[d], 1);
  }
}

__global__ void k_dinv(const int* __restrict__ cnt, float* __restrict__ dinv) {
  int v = blockIdx.x * blockDim.x + threadIdx.x;
  if (v < NNODES) dinv[v] = rsqrtf((float)cnt[v] + 1.0f);
}

// ---------- simple chunk-serial scan (validated structure) ----------
__global__ void k_scan2(const int* __restrict__ cnt, int* __restrict__ offs,
                        int* __restrict__ cursor) {
  __shared__ int chunk[257];
  const int t = threadIdx.x;            // 256 threads
  const int lo = t * 391;
  const int hi = (lo + 391 < NNODES) ? lo + 391 : NNODES;
  int s = 0;
  for (int i = lo; i < hi; ++i) s += cnt[i];
  chunk[t] = s;
  __syncthreads();
  if (t == 0) {
    int acc = 0;
    for (int i = 0; i < 256; ++i) { int c = chunk[i]; chunk[i] = acc; acc += c; }
    offs[NNODES] = acc;
  }
  __syncthreads();
  int acc = chunk[t];
  for (int i = lo; i < hi; ++i) { offs[i] = acc; cursor[i] = acc; acc += cnt[i]; }
}

__global__ void k_fill(const int* __restrict__ ei, int* __restrict__ cursor,
                       int* __restrict__ csr_src, float* __restrict__ csr_coef,
                       const float* __restrict__ dinv, const int* __restrict__ flags) {
  int e = blockIdx.x * blockDim.x + threadIdx.x;
  if (e < NEDGES) {
    int i64 = flags[1];
    int s = edge_at(ei, e, i64), d = edge_at(ei, NEDGES + e, i64);
    if ((unsigned)s < NNODES && (unsigned)d < NNODES) {
      int p = atomicAdd(&cursor[d], 1);
      if ((unsigned)p < NEDGES) {
        csr_src[p] = s;
        csr_coef[p] = dinv[s] * dinv[d];
      }
    }
  }
}

// ---------- aggregation: one wave per node, CSR gather, fp32 accum ----------
template <int D>
__global__ __launch_bounds__(256) void k_agg(
    const unsigned short* __restrict__ hin, unsigned short* __restrict__ hout,
    const int* __restrict__ offs, const int* __restrict__ csr_src,
    const float* __restrict__ csr_coef, const float* __restrict__ dinv) {
  constexpr int PER = D / 64;  // 2 or 4
  int w = (blockIdx.x * 256 + threadIdx.x) >> 6;
  int lane = threadIdx.x & 63;
  if (w >= NNODES) return;
  float dv = dinv[w];
  float acc[PER];
  size_t base = (size_t)w * D + lane * PER;
  if (PER == 4) {
    uint2 u = *(const uint2*)(hin + base);
    acc[0] = bf2f(u.x & 0xffffu) * dv * dv;
    acc[1] = bf2f(u.x >> 16) * dv * dv;
    acc[2] = bf2f(u.y & 0xffffu) * dv * dv;
    acc[3] = bf2f(u.y >> 16) * dv * dv;
  } else {
    unsigned u = *(const unsigned*)(hin + base);
    acc[0] = bf2f(u & 0xffffu) * dv * dv;
    acc[1] = bf2f(u >> 16) * dv * dv;
  }
  int b = offs[w], e = offs[w + 1];
  for (int i = b; i < e; ++i) {
    int s = csr_src[i];
    s = ((unsigned)s < NNODES) ? s : 0;   // clamp: no wild reads
    float c = csr_coef[i];
    size_t sb = (size_t)s * D + lane * PER;
    if (PER == 4) {
      uint2 u = *(const uint2*)(hin + sb);
      acc[0] += c * bf2f(u.x & 0xffffu);
      acc[1] += c * bf2f(u.x >> 16);
      acc[2] += c * bf2f(u.y & 0xffffu);
      acc[3] += c * bf2f(u.y >> 16);
    } else {
      unsigned u = *(const unsigned*)(hin + sb);
      acc[0] += c * bf2f(u & 0xffffu);
      acc[1] += c * bf2f(u >> 16);
    }
  }
  if (PER == 4) {
    uint2 o;
    o.x = (unsigned)f2bf(acc[0]) | ((unsigned)f2bf(acc[1]) << 16);
    o.y = (unsigned)f2bf(acc[2]) | ((unsigned)f2bf(acc[3]) << 16);
    *(uint2*)(hout + base) = o;
  } else {
    *(unsigned*)(hout + base) =
        (unsigned)f2bf(acc[0]) | ((unsigned)f2bf(acc[1]) << 16);
  }
}

// ---------- continue GEMM: out = relu(A[N,K] @ W[K,256] + b), bf16 ----------
template <int K>
__global__ __launch_bounds__(256) void k_mlp256(
    const unsigned short* __restrict__ A, const unsigned short* __restrict__ W,
    const unsigned short* __restrict__ bias, unsigned short* __restrict__ out) {
  __shared__ float sA[16][64];    // [k][node]
  __shared__ float sW[16][256];   // [k][col]
  const int t = threadIdx.x;
  const int m0 = blockIdx.x * 64;
  const int jg = t & 31, ng = t >> 5;
  const int j0 = jg * 8, n0 = ng * 8;
  float acc[8][8];
#pragma unroll
  for (int i = 0; i < 8; ++i)
#pragma unroll
    for (int j = 0; j < 8; ++j) acc[i][j] = 0.f;

  for (int kc = 0; kc < K / 16; ++kc) {
    __syncthreads();
    {  // stage A: 64 rows x 16 k (transposed)
      int r = t >> 2, q = t & 3;
      uint2 u = make_uint2(0, 0);
      int row = m0 + r;
      if (row < NNODES) u = *(const uint2*)(A + (size_t)row * K + kc * 16 + q * 4);
      sA[q * 4 + 0][r] = bf2f(u.x & 0xffffu);
      sA[q * 4 + 1][r] = bf2f(u.x >> 16);
      sA[q * 4 + 2][r] = bf2f(u.y & 0xffffu);
      sA[q * 4 + 3][r] = bf2f(u.y >> 16);
    }
    {  // stage W: 16 k x 256 cols
      int kl = t >> 4, c0 = (t & 15) * 16;
      const unsigned short* wp = W + (size_t)(kc * 16 + kl) * 256 + c0;
      uint4 u0 = *(const uint4*)wp;
      uint4 u1 = *(const uint4*)(wp + 8);
      float4 f;
      f.x = bf2f(u0.x & 0xffffu); f.y = bf2f(u0.x >> 16);
      f.z = bf2f(u0.y & 0xffffu); f.w = bf2f(u0.y >> 16);
      *(float4*)&sW[kl][c0] = f;
      f.x = bf2f(u0.z & 0xffffu); f.y = bf2f(u0.z >> 16);
      f.z = bf2f(u0.w & 0xffffu); f.w = bf2f(u0.w >> 16);
      *(float4*)&sW[kl][c0 + 4] = f;
      f.x = bf2f(u1.x & 0xffffu); f.y = bf2f(u1.x >> 16);
      f.z = bf2f(u1.y & 0xffffu); f.w = bf2f(u1.y >> 16);
      *(float4*)&sW[kl][c0 + 8] = f;
      f.x = bf2f(u1.z & 0xffffu); f.y = bf2f(u1.z >> 16);
      f.z = bf2f(u1.w & 0xffffu); f.w = bf2f(u1.w >> 16);
      *(float4*)&sW[kl][c0 + 12] = f;
    }
    __syncthreads();
#pragma unroll
    for (int k = 0; k < 16; ++k) {
      float4 a0 = *(const float4*)&sA[k][n0];
      float4 a1 = *(const float4*)&sA[k][n0 + 4];
      float4 w0 = *(const float4*)&sW[k][j0];
      float4 w1 = *(const float4*)&sW[k][j0 + 4];
      float av[8] = {a0.x, a0.y, a0.z, a0.w, a1.x, a1.y, a1.z, a1.w};
      float wv[8] = {w0.x, w0.y, w0.z, w0.w, w1.x, w1.y, w1.z, w1.w};
#pragma unroll
      for (int i = 0; i < 8; ++i)
#pragma unroll
        for (int j = 0; j < 8; ++j) acc[i][j] += av[i] * wv[j];
    }
  }
  float bv[8];
#pragma unroll
  for (int j = 0; j < 8; ++j) bv[j] = bf2f((unsigned)bias[j0 + j]);
#pragma unroll
  for (int i = 0; i < 8; ++i) {
    int row = m0 + n0 + i;
    if (row < NNODES) {
      float v[8];
#pragma unroll
      for (int j = 0; j < 8; ++j) v[j] = fmaxf(acc[i][j] + bv[j], 0.f);
      uint4 o;
      o.x = (unsigned)f2bf(v[0]) | ((unsigned)f2bf(v[1]) << 16);
      o.y = (unsigned)f2bf(v[2]) | ((unsigned)f2bf(v[3]) << 16);
      o.z = (unsigned)f2bf(v[4]) | ((unsigned)f2bf(v[5]) << 16);
      o.w = (unsigned)f2bf(v[6]) | ((unsigned)f2bf(v[7]) << 16);
      *(uint4*)(out + (size_t)row * 256 + j0) = o;
    }
  }
}

// ---------- exit GEMM + fused log_softmax: FP32 output ----------
template <int K>
__global__ __launch_bounds__(256) void k_exit(
    const unsigned short* __restrict__ A, const unsigned short* __restrict__ W,
    const unsigned short* __restrict__ bias, float* __restrict__ outp) {
  __shared__ float sA[16][128];  // [k][node]
  __shared__ float sW[16][48];   // [k][padded col]
  __shared__ float sO[128][41];
  const int t = threadIdx.x;
  const int m0 = blockIdx.x * 128;
  const int ng = t >> 2, jg = t & 3;
  const int n0 = ng * 2, j0 = jg * 10, jw = jg * 12;
  float bv[10];
#pragma unroll
  for (int j = 0; j < 10; ++j) bv[j] = bf2f((unsigned)bias[j0 + j]);
  float acc[2][10];
#pragma unroll
  for (int i = 0; i < 2; ++i)
#pragma unroll
    for (int j = 0; j < 10; ++j) acc[i][j] = 0.f;

  for (int kc = 0; kc < K / 16; ++kc) {
    __syncthreads();
    {  // stage A: 128 rows x 16 k
      int r = t >> 1, half = t & 1;
      uint4 u = make_uint4(0, 0, 0, 0);
      int row = m0 + r;
      if (row < NNODES) u = *(const uint4*)(A + (size_t)row * K + kc * 16 + half * 8);
      int kb = half * 8;
      sA[kb + 0][r] = bf2f(u.x & 0xffffu);
      sA[kb + 1][r] = bf2f(u.x >> 16);
      sA[kb + 2][r] = bf2f(u.y & 0xffffu);
      sA[kb + 3][r] = bf2f(u.y >> 16);
      sA[kb + 4][r] = bf2f(u.z & 0xffffu);
      sA[kb + 5][r] = bf2f(u.z >> 16);
      sA[kb + 6][r] = bf2f(u.w & 0xffffu);
      sA[kb + 7][r] = bf2f(u.w >> 16);
    }
    for (int e = t; e < 640; e += 256) {  // stage W: 16 k x 40 cols (padded)
      int kl = e / 40, j = e % 40;
      sW[kl][(j / 10) * 12 + (j % 10)] = bf2f((unsigned)W[(size_t)(kc * 16 + kl) * 40 + j]);
    }
    __syncthreads();
#pragma unroll
    for (int k = 0; k < 16; ++k) {
      float2 a = *(const float2*)&sA[k][n0];
      float4 w0 = *(const float4*)&sW[k][jw];
      float4 w1 = *(const float4*)&sW[k][jw + 4];
      float2 w2 = *(const float2*)&sW[k][jw + 8];
      float wv[10] = {w0.x, w0.y, w0.z, w0.w, w1.x, w1.y, w1.z, w1.w, w2.x, w2.y};
#pragma unroll
      for (int j = 0; j < 10; ++j) {
        acc[0][j] += a.x * wv[j];
        acc[1][j] += a.y * wv[j];
      }
    }
  }
  __syncthreads();
#pragma unroll
  for (int i = 0; i < 2; ++i)
#pragma unroll
    for (int j = 0; j < 10; ++j) sO[n0 + i][j0 + j] = acc[i][j] + bv[j];
  __syncthreads();
  if (t < 128) {
    int row = m0 + t;
    if (row < NNODES) {
      float m = -1e30f;
#pragma unroll
      for (int j = 0; j < 40; ++j) m = fmaxf(m, sO[t][j]);
      float ssum = 0.f;
#pragma unroll
      for (int j = 0; j < 40; ++j) ssum += expf(sO[t][j] - m);
      float ls = logf(ssum) + m;
#pragma unroll
      for (int j = 0; j < 40; ++j)
        outp[(size_t)row * 160 + j] = sO[t][j] - ls;   // FP32 write
    }
  }
}

// ---------- launch ----------
extern "C" void kernel_launch(void* const* d_in, const int* in_sizes, int n_in,
                              void* d_out, int out_size, void* d_ws, size_t ws_size,
                              hipStream_t stream) {
  const void* x_raw   = d_in[0];
  const int* ei       = (const int*)d_in[1];
  float* out          = (float*)d_out;   // reference output dtype = float32

  char* ws = (char*)d_ws;
  int*   flags    = (int*)(ws + 0);
  int*   cnt      = (int*)(ws + 4096);
  int*   offs     = (int*)(ws + 524288);
  int*   cursor   = (int*)(ws + 1048576);
  float* dinv     = (float*)(ws + 1572864);
  int*   csr_src  = (int*)(ws + 2097152);       // 6.4 MB
  float* csr_coef = (float*)(ws + 9437184);     // 6.4 MB
  unsigned short* xb = (unsigned short*)(ws + 16777216);   // N*128 bf16
  unsigned short* wb = (unsigned short*)(ws + 45088768);   // weights
  unsigned short* hA = (unsigned short*)(ws + 48234496);   // N*256 bf16
  unsigned short* hB = (unsigned short*)(ws + 100663296);  // N*256 bf16

  unsigned short* Wc0 = wb + 0;       // 128*256
  unsigned short* bc0 = wb + 32768;   // 256
  unsigned short* Wc1 = wb + 33024;   // 256*256
  unsigned short* bc1 = wb + 98560;   // 256
  unsigned short* We0 = wb + 98816;   // 128*40
  unsigned short* be0 = wb + 103936;  // 40
  unsigned short* We1 = wb + 103976;  // 128*40
  unsigned short* be1 = wb + 109096;  // 40
  unsigned short* We2 = wb + 109136;  // 256*40
  unsigned short* be2 = wb + 119376;  // 40
  unsigned short* We3 = wb + 119416;  // 256*40
  unsigned short* be3 = wb + 129656;  // 40

  int ok = (n_in >= 16 && in_sizes[0] == 12800000 && in_sizes[1] == 3200000 &&
            in_sizes[2] == 32768 && in_sizes[4] == 65536 && in_sizes[8] == 5120 &&
            in_sizes[12] == 10240) ? 1 : 0;

  dim3 B(256);
  k_probe<<<dim3(1), B, 0, stream>>>((const unsigned*)x_raw, ei, flags);
  k_sentinel<<<dim3(4096), B, 0, stream>>>(out, flags, ok);
  k_zero<<<dim3(391), B, 0, stream>>>(cnt, NNODES);
  k_zero<<<dim3(6250), B, 0, stream>>>(csr_src, NEDGES);

  CvtParams p;
  const int srcIdx[13] = {0, 2, 3, 4, 5, 8, 9, 10, 11, 12, 13, 14, 15};
  unsigned short* dsts[13] = {xb, Wc0, bc0, Wc1, bc1, We0, be0, We1, be1, We2, be2, We3, be3};
  const int ns[13] = {NNODES * 128, 128 * 256, 256, 256 * 256, 256,
                      128 * 40, 40, 128 * 40, 40, 256 * 40, 40, 256 * 40, 40};
  for (int i = 0; i < 13; ++i) { p.src[i] = d_in[srcIdx[i]]; p.dst[i] = dsts[i]; p.n[i] = ns[i]; }
  k_cvt<<<dim3(1024, 13), B, 0, stream>>>(p, flags);

  k_count<<<dim3((NEDGES + 255) / 256), B, 0, stream>>>(ei, cnt, flags);
  k_dinv<<<dim3((NNODES + 255) / 256), B, 0, stream>>>(cnt, dinv);
  k_scan2<<<dim3(1), B, 0, stream>>>(cnt, offs, cursor);
  k_fill<<<dim3((NEDGES + 255) / 256), B, 0, stream>>>(ei, cursor, csr_src, csr_coef, dinv, flags);

  // layer 0: on x
  k_exit<128><<<dim3(782), B, 0, stream>>>(xb, We0, be0, out + 0 * 40);
  // h1 = agg(x)
  k_agg<128><<<dim3(25000), B, 0, stream>>>(xb, hA, offs, csr_src, csr_coef, dinv);
  k_exit<128><<<dim3(782), B, 0, stream>>>(hA, We1, be1, out + 1 * 40);
  k_mlp256<128><<<dim3(1563), B, 0, stream>>>(hA, Wc0, bc0, hB);
  // h2 = agg(relu(h1 Wc0 + bc0))
  k_agg<256><<<dim3(25000), B, 0, stream>>>(hB, hA, offs, csr_src, csr_coef, dinv);
  k_exit<256><<<dim3(782), B, 0, stream>>>(hA, We2, be2, out + 2 * 40);
  k_mlp256<256><<<dim3(1563), B, 0, stream>>>(hA, Wc1, bc1, hB);
  // h3 = agg(relu(h2 Wc1 + bc1))
  k_agg<256><<<dim3(25000), B, 0, stream>>>(hB, hA, offs, csr_src, csr_coef, dinv);
  k_exit<256><<<dim3(782), B, 0, stream>>>(hA, We3, be3, out + 3 * 40);
}

// Round 5
// 1289.292 us; speedup vs baseline: 1.1943x; 1.1943x over previous
//
#include <hip/hip_runtime.h>

#define NNODES 100000
#define NEDGES 1600000

// ---------- bf16 helpers ----------
__device__ __forceinline__ float bf2f(unsigned v) {
  union { unsigned u; float f; } x; x.u = v << 16; return x.f;
}
__device__ __forceinline__ unsigned short f2bf(float f) {
  union { float f; unsigned u; } x; x.f = f;
  unsigned r = x.u + 0x7fffu + ((x.u >> 16) & 1u);
  return (unsigned short)(r >> 16);
}

// ---------- dtype probing ----------
// flags[0] = 1 if float inputs are fp32 (else bf16)
// flags[1] = 1 if edge_index is int64 (else int32)
__global__ void k_probe(const unsigned* __restrict__ xw, const int* __restrict__ ei,
                        int* __restrict__ flags) {
  __shared__ int cF, cI;
  if (threadIdx.x == 0) { cF = 0; cI = 0; }
  __syncthreads();
  int t = threadIdx.x;
  int hf = 0;
  for (int i = t; i < 2048; i += 256) {
    unsigned lo = xw[i] & 0xffffu;
    unsigned e = (lo >> 7) & 0xffu;
    if (e >= 0xC0u) hf++;
  }
  atomicAdd(&cF, hf);
  int hi = 0;
  if (ei[2 * t + 1] != 0) hi++;
  atomicAdd(&cI, hi);
  __syncthreads();
  if (threadIdx.x == 0) {
    flags[0] = (cF > 32) ? 1 : 0;
    flags[1] = (cI < 16) ? 1 : 0;
  }
}

__device__ __forceinline__ int edge_at(const int* __restrict__ ei, int j, int i64) {
  return i64 ? ei[2 * j] : ei[j];
}

// ---------- canonicalize float arrays to bf16 ----------
struct CvtParams {
  const void* src[13];
  unsigned short* dst[13];
  int n[13];
};

__global__ void k_cvt(CvtParams p, const int* __restrict__ flags) {
  int a = blockIdx.y;
  int n = p.n[a];
  int f32 = flags[0];
  const float* sf = (const float*)p.src[a];
  const unsigned short* sb = (const unsigned short*)p.src[a];
  unsigned short* d = p.dst[a];
  for (int i = blockIdx.x * blockDim.x + threadIdx.x; i < n; i += gridDim.x * blockDim.x) {
    d[i] = f32 ? f2bf(sf[i]) : sb[i];
  }
}

__global__ void k_zero(int* __restrict__ p, int n) {
  int v = blockIdx.x * blockDim.x + threadIdx.x;
  if (v < n) p[v] = 0;
}

// ---------- graph preprocessing ----------
__global__ void k_count(const int* __restrict__ ei, int* __restrict__ cnt,
                        const int* __restrict__ flags) {
  int e = blockIdx.x * blockDim.x + threadIdx.x;
  if (e < NEDGES) {
    int i64 = flags[1];
    int d = edge_at(ei, NEDGES + e, i64);
    if ((unsigned)d < NNODES) atomicAdd(&cnt[d], 1);
  }
}

__global__ void k_dinv(const int* __restrict__ cnt, float* __restrict__ dinv) {
  int v = blockIdx.x * blockDim.x + threadIdx.x;
  if (v < NNODES) dinv[v] = rsqrtf((float)cnt[v] + 1.0f);
}

// ---------- parallel scan: block sums -> 1-wave scan -> scatter ----------
__global__ void k_psum(const int* __restrict__ cnt, int* __restrict__ bsum) {
  __shared__ int sw[4];
  int t = threadIdx.x;
  int i = blockIdx.x * 256 + t;
  int v = (i < NNODES) ? cnt[i] : 0;
  int x = v;
#pragma unroll
  for (int o = 1; o < 64; o <<= 1) {
    int y = __shfl_up(x, o, 64);
    if ((t & 63) >= o) x += y;
  }
  if ((t & 63) == 63) sw[t >> 6] = x;
  __syncthreads();
  if (t == 0) bsum[blockIdx.x] = sw[0] + sw[1] + sw[2] + sw[3];
}

__global__ void k_bscan(const int* __restrict__ bsum, int* __restrict__ bbase,
                        int* __restrict__ offs) {
  // 1 wave; 391 entries, 7 per lane
  int l = threadIdx.x;
  int base = l * 7;
  int v[7];
  int s = 0;
#pragma unroll
  for (int k = 0; k < 7; ++k) {
    int j = base + k;
    v[k] = (j < 391) ? bsum[j] : 0;
    s += v[k];
  }
  int x = s;
#pragma unroll
  for (int o = 1; o < 64; o <<= 1) {
    int y = __shfl_up(x, o, 64);
    if (l >= o) x += y;
  }
  int excl = x - s;
#pragma unroll
  for (int k = 0; k < 7; ++k) {
    int j = base + k;
    if (j < 391) bbase[j] = excl;
    excl += v[k];
  }
  if (l == 63) offs[NNODES] = x;  // total == NEDGES
}

__global__ void k_offs(const int* __restrict__ cnt, const int* __restrict__ bbase,
                       int* __restrict__ offs, int* __restrict__ cursor) {
  __shared__ int sw[4], swo[4];
  int t = threadIdx.x;
  int i = blockIdx.x * 256 + t;
  int v = (i < NNODES) ? cnt[i] : 0;
  int x = v;
#pragma unroll
  for (int o = 1; o < 64; o <<= 1) {
    int y = __shfl_up(x, o, 64);
    if ((t & 63) >= o) x += y;
  }
  if ((t & 63) == 63) sw[t >> 6] = x;
  __syncthreads();
  if (t == 0) {
    int a = 0;
#pragma unroll
    for (int w = 0; w < 4; ++w) { swo[w] = a; a += sw[w]; }
  }
  __syncthreads();
  if (i < NNODES) {
    int e = bbase[blockIdx.x] + swo[t >> 6] + x - v;
    offs[i] = e;
    cursor[i] = e;
  }
}

__global__ void k_fill(const int* __restrict__ ei, int* __restrict__ cursor,
                       int* __restrict__ csr_src, float* __restrict__ csr_coef,
                       const float* __restrict__ dinv, const int* __restrict__ flags) {
  int e = blockIdx.x * blockDim.x + threadIdx.x;
  if (e < NEDGES) {
    int i64 = flags[1];
    int s = edge_at(ei, e, i64), d = edge_at(ei, NEDGES + e, i64);
    if ((unsigned)s < NNODES && (unsigned)d < NNODES) {
      int p = atomicAdd(&cursor[d], 1);
      if ((unsigned)p < NEDGES) {
        csr_src[p] = s;
        csr_coef[p] = dinv[s] * dinv[d];
      }
    }
  }
}

// ---------- aggregation: one wave per node, CSR gather, fp32 accum ----------
template <int D>
__global__ __launch_bounds__(256) void k_agg(
    const unsigned short* __restrict__ hin, unsigned short* __restrict__ hout,
    const int* __restrict__ offs, const int* __restrict__ csr_src,
    const float* __restrict__ csr_coef, const float* __restrict__ dinv) {
  constexpr int PER = D / 64;  // 2 or 4
  int w = (blockIdx.x * 256 + threadIdx.x) >> 6;
  int lane = threadIdx.x & 63;
  if (w >= NNODES) return;
  float dv = dinv[w];
  float acc[PER];
  size_t base = (size_t)w * D + lane * PER;
  if (PER == 4) {
    uint2 u = *(const uint2*)(hin + base);
    acc[0] = bf2f(u.x & 0xffffu) * dv * dv;
    acc[1] = bf2f(u.x >> 16) * dv * dv;
    acc[2] = bf2f(u.y & 0xffffu) * dv * dv;
    acc[3] = bf2f(u.y >> 16) * dv * dv;
  } else {
    unsigned u = *(const unsigned*)(hin + base);
    acc[0] = bf2f(u & 0xffffu) * dv * dv;
    acc[1] = bf2f(u >> 16) * dv * dv;
  }
  int b = offs[w], e = offs[w + 1];
  for (int i = b; i < e; ++i) {
    int s = csr_src[i];
    s = ((unsigned)s < NNODES) ? s : 0;
    float c = csr_coef[i];
    size_t sb = (size_t)s * D + lane * PER;
    if (PER == 4) {
      uint2 u = *(const uint2*)(hin + sb);
      acc[0] += c * bf2f(u.x & 0xffffu);
      acc[1] += c * bf2f(u.x >> 16);
      acc[2] += c * bf2f(u.y & 0xffffu);
      acc[3] += c * bf2f(u.y >> 16);
    } else {
      unsigned u = *(const unsigned*)(hin + sb);
      acc[0] += c * bf2f(u & 0xffffu);
      acc[1] += c * bf2f(u >> 16);
    }
  }
  if (PER == 4) {
    uint2 o;
    o.x = (unsigned)f2bf(acc[0]) | ((unsigned)f2bf(acc[1]) << 16);
    o.y = (unsigned)f2bf(acc[2]) | ((unsigned)f2bf(acc[3]) << 16);
    *(uint2*)(hout + base) = o;
  } else {
    *(unsigned*)(hout + base) =
        (unsigned)f2bf(acc[0]) | ((unsigned)f2bf(acc[1]) << 16);
  }
}

// ---------- width-40 aggregation + bias + log_softmax (layer 3) ----------
__global__ __launch_bounds__(256) void k_agg40(
    const unsigned short* __restrict__ P, const int* __restrict__ offs,
    const int* __restrict__ csr_src, const float* __restrict__ csr_coef,
    const float* __restrict__ dinv, const unsigned short* __restrict__ bias,
    float* __restrict__ outp) {
  int w = (blockIdx.x * 256 + threadIdx.x) >> 6;
  int lane = threadIdx.x & 63;
  if (w >= NNODES) return;
  float dv = dinv[w];
  float a0 = 0.f, a1 = 0.f;
  if (lane < 20) {
    unsigned u = *(const unsigned*)(P + (size_t)w * 40 + lane * 2);
    a0 = bf2f(u & 0xffffu) * dv * dv;
    a1 = bf2f(u >> 16) * dv * dv;
  }
  int b = offs[w], e = offs[w + 1];
  for (int i = b; i < e; ++i) {
    int s = csr_src[i];
    s = ((unsigned)s < NNODES) ? s : 0;
    float c = csr_coef[i];
    if (lane < 20) {
      unsigned u = *(const unsigned*)(P + (size_t)s * 40 + lane * 2);
      a0 += c * bf2f(u & 0xffffu);
      a1 += c * bf2f(u >> 16);
    }
  }
  if (lane < 20) {
    a0 += bf2f((unsigned)bias[lane * 2]);
    a1 += bf2f((unsigned)bias[lane * 2 + 1]);
  }
  float m = (lane < 20) ? fmaxf(a0, a1) : -1e30f;
#pragma unroll
  for (int o = 16; o > 0; o >>= 1) m = fmaxf(m, __shfl_xor(m, o, 32));
  float ss = (lane < 20) ? (expf(a0 - m) + expf(a1 - m)) : 0.f;
#pragma unroll
  for (int o = 16; o > 0; o >>= 1) ss += __shfl_xor(ss, o, 32);
  float ls = logf(ss) + m;
  if (lane < 20) {
    float2 o2;
    o2.x = a0 - ls;
    o2.y = a1 - ls;
    *(float2*)(outp + (size_t)w * 160 + lane * 2) = o2;
  }
}

// ---------- continue GEMM: out = relu(A[N,K] @ W[K,256] + b), bf16 ----------
template <int K>
__global__ __launch_bounds__(256) void k_mlp256(
    const unsigned short* __restrict__ A, const unsigned short* __restrict__ W,
    const unsigned short* __restrict__ bias, unsigned short* __restrict__ out) {
  __shared__ float sA[16][64];
  __shared__ float sW[16][256];
  const int t = threadIdx.x;
  const int m0 = blockIdx.x * 64;
  const int jg = t & 31, ng = t >> 5;
  const int j0 = jg * 8, n0 = ng * 8;
  float acc[8][8];
#pragma unroll
  for (int i = 0; i < 8; ++i)
#pragma unroll
    for (int j = 0; j < 8; ++j) acc[i][j] = 0.f;

  for (int kc = 0; kc < K / 16; ++kc) {
    __syncthreads();
    {
      int r = t >> 2, q = t & 3;
      uint2 u = make_uint2(0, 0);
      int row = m0 + r;
      if (row < NNODES) u = *(const uint2*)(A + (size_t)row * K + kc * 16 + q * 4);
      sA[q * 4 + 0][r] = bf2f(u.x & 0xffffu);
      sA[q * 4 + 1][r] = bf2f(u.x >> 16);
      sA[q * 4 + 2][r] = bf2f(u.y & 0xffffu);
      sA[q * 4 + 3][r] = bf2f(u.y >> 16);
    }
    {
      int kl = t >> 4, c0 = (t & 15) * 16;
      const unsigned short* wp = W + (size_t)(kc * 16 + kl) * 256 + c0;
      uint4 u0 = *(const uint4*)wp;
      uint4 u1 = *(const uint4*)(wp + 8);
      float4 f;
      f.x = bf2f(u0.x & 0xffffu); f.y = bf2f(u0.x >> 16);
      f.z = bf2f(u0.y & 0xffffu); f.w = bf2f(u0.y >> 16);
      *(float4*)&sW[kl][c0] = f;
      f.x = bf2f(u0.z & 0xffffu); f.y = bf2f(u0.z >> 16);
      f.z = bf2f(u0.w & 0xffffu); f.w = bf2f(u0.w >> 16);
      *(float4*)&sW[kl][c0 + 4] = f;
      f.x = bf2f(u1.x & 0xffffu); f.y = bf2f(u1.x >> 16);
      f.z = bf2f(u1.y & 0xffffu); f.w = bf2f(u1.y >> 16);
      *(float4*)&sW[kl][c0 + 8] = f;
      f.x = bf2f(u1.z & 0xffffu); f.y = bf2f(u1.z >> 16);
      f.z = bf2f(u1.w & 0xffffu); f.w = bf2f(u1.w >> 16);
      *(float4*)&sW[kl][c0 + 12] = f;
    }
    __syncthreads();
#pragma unroll
    for (int k = 0; k < 16; ++k) {
      float4 a0 = *(const float4*)&sA[k][n0];
      float4 a1 = *(const float4*)&sA[k][n0 + 4];
      float4 w0 = *(const float4*)&sW[k][j0];
      float4 w1 = *(const float4*)&sW[k][j0 + 4];
      float av[8] = {a0.x, a0.y, a0.z, a0.w, a1.x, a1.y, a1.z, a1.w};
      float wv[8] = {w0.x, w0.y, w0.z, w0.w, w1.x, w1.y, w1.z, w1.w};
#pragma unroll
      for (int i = 0; i < 8; ++i)
#pragma unroll
        for (int j = 0; j < 8; ++j) acc[i][j] += av[i] * wv[j];
    }
  }
  float bv[8];
#pragma unroll
  for (int j = 0; j < 8; ++j) bv[j] = bf2f((unsigned)bias[j0 + j]);
#pragma unroll
  for (int i = 0; i < 8; ++i) {
    int row = m0 + n0 + i;
    if (row < NNODES) {
      float v[8];
#pragma unroll
      for (int j = 0; j < 8; ++j) v[j] = fmaxf(acc[i][j] + bv[j], 0.f);
      uint4 o;
      o.x = (unsigned)f2bf(v[0]) | ((unsigned)f2bf(v[1]) << 16);
      o.y = (unsigned)f2bf(v[2]) | ((unsigned)f2bf(v[3]) << 16);
      o.z = (unsigned)f2bf(v[4]) | ((unsigned)f2bf(v[5]) << 16);
      o.w = (unsigned)f2bf(v[6]) | ((unsigned)f2bf(v[7]) << 16);
      *(uint4*)(out + (size_t)row * 256 + j0) = o;
    }
  }
}

// ---------- exit GEMM core (shared by softmax-out and P-out variants) ----------
template <int K, bool SOFTMAX>
__global__ __launch_bounds__(256) void k_exit(
    const unsigned short* __restrict__ A, const unsigned short* __restrict__ W,
    const unsigned short* __restrict__ bias, float* __restrict__ outp,
    unsigned short* __restrict__ Pout) {
  __shared__ float sA[16][128];
  __shared__ float sW[16][48];
  __shared__ float sO[128][41];
  const int t = threadIdx.x;
  const int m0 = blockIdx.x * 128;
  const int ng = t >> 2, jg = t & 3;
  const int n0 = ng * 2, j0 = jg * 10, jw = jg * 12;
  float acc[2][10];
#pragma unroll
  for (int i = 0; i < 2; ++i)
#pragma unroll
    for (int j = 0; j < 10; ++j) acc[i][j] = 0.f;

  for (int kc = 0; kc < K / 16; ++kc) {
    __syncthreads();
    {
      int r = t >> 1, half = t & 1;
      uint4 u = make_uint4(0, 0, 0, 0);
      int row = m0 + r;
      if (row < NNODES) u = *(const uint4*)(A + (size_t)row * K + kc * 16 + half * 8);
      int kb = half * 8;
      sA[kb + 0][r] = bf2f(u.x & 0xffffu);
      sA[kb + 1][r] = bf2f(u.x >> 16);
      sA[kb + 2][r] = bf2f(u.y & 0xffffu);
      sA[kb + 3][r] = bf2f(u.y >> 16);
      sA[kb + 4][r] = bf2f(u.z & 0xffffu);
      sA[kb + 5][r] = bf2f(u.z >> 16);
      sA[kb + 6][r] = bf2f(u.w & 0xffffu);
      sA[kb + 7][r] = bf2f(u.w >> 16);
    }
    for (int e = t; e < 640; e += 256) {
      int kl = e / 40, j = e % 40;
      sW[kl][(j / 10) * 12 + (j % 10)] = bf2f((unsigned)W[(size_t)(kc * 16 + kl) * 40 + j]);
    }
    __syncthreads();
#pragma unroll
    for (int k = 0; k < 16; ++k) {
      float2 a = *(const float2*)&sA[k][n0];
      float4 w0 = *(const float4*)&sW[k][jw];
      float4 w1 = *(const float4*)&sW[k][jw + 4];
      float2 w2 = *(const float2*)&sW[k][jw + 8];
      float wv[10] = {w0.x, w0.y, w0.z, w0.w, w1.x, w1.y, w1.z, w1.w, w2.x, w2.y};
#pragma unroll
      for (int j = 0; j < 10; ++j) {
        acc[0][j] += a.x * wv[j];
        acc[1][j] += a.y * wv[j];
      }
    }
  }

  if (SOFTMAX) {
    float bv[10];
#pragma unroll
    for (int j = 0; j < 10; ++j) bv[j] = bf2f((unsigned)bias[j0 + j]);
    __syncthreads();
#pragma unroll
    for (int i = 0; i < 2; ++i)
#pragma unroll
      for (int j = 0; j < 10; ++j) sO[n0 + i][j0 + j] = acc[i][j] + bv[j];
    __syncthreads();
    if (t < 128) {
      int row = m0 + t;
      if (row < NNODES) {
        float m = -1e30f;
#pragma unroll
        for (int j = 0; j < 40; ++j) m = fmaxf(m, sO[t][j]);
        float ssum = 0.f;
#pragma unroll
        for (int j = 0; j < 40; ++j) ssum += expf(sO[t][j] - m);
        float ls = logf(ssum) + m;
#pragma unroll
        for (int j = 0; j < 40; ++j)
          outp[(size_t)row * 160 + j] = sO[t][j] - ls;
      }
    }
  } else {
    // write raw A@W (no bias) as bf16 into Pout[N,40]
#pragma unroll
    for (int i = 0; i < 2; ++i) {
      int row = m0 + n0 + i;
      if (row < NNODES) {
#pragma unroll
        for (int j = 0; j < 10; j += 2) {
          unsigned o = (unsigned)f2bf(acc[i][j]) | ((unsigned)f2bf(acc[i][j + 1]) << 16);
          *(unsigned*)(Pout + (size_t)row * 40 + j0 + j) = o;
        }
      }
    }
  }
}

// ---------- launch ----------
extern "C" void kernel_launch(void* const* d_in, const int* in_sizes, int n_in,
                              void* d_out, int out_size, void* d_ws, size_t ws_size,
                              hipStream_t stream) {
  const void* x_raw   = d_in[0];
  const int* ei       = (const int*)d_in[1];
  float* out          = (float*)d_out;

  char* ws = (char*)d_ws;
  int*   flags    = (int*)(ws + 0);
  int*   bsum     = (int*)(ws + 1024);
  int*   bbase    = (int*)(ws + 2816);
  int*   cnt      = (int*)(ws + 8192);
  int*   offs     = (int*)(ws + 524288);
  int*   cursor   = (int*)(ws + 1048576);
  float* dinv     = (float*)(ws + 1572864);
  int*   csr_src  = (int*)(ws + 2097152);       // 6.4 MB
  float* csr_coef = (float*)(ws + 9437184);     // 6.4 MB
  unsigned short* xb = (unsigned short*)(ws + 16777216);   // N*128 bf16 (reused as P[N,40] at step 3)
  unsigned short* wb = (unsigned short*)(ws + 45088768);   // weights
  unsigned short* hA = (unsigned short*)(ws + 48234496);   // N*256 bf16
  unsigned short* hB = (unsigned short*)(ws + 100663296);  // N*256 bf16
  unsigned short* P  = xb;  // xb is dead after k_agg<128>

  unsigned short* Wc0 = wb + 0;
  unsigned short* bc0 = wb + 32768;
  unsigned short* Wc1 = wb + 33024;
  unsigned short* bc1 = wb + 98560;
  unsigned short* We0 = wb + 98816;
  unsigned short* be0 = wb + 103936;
  unsigned short* We1 = wb + 103976;
  unsigned short* be1 = wb + 109096;
  unsigned short* We2 = wb + 109136;
  unsigned short* be2 = wb + 119376;
  unsigned short* We3 = wb + 119416;
  unsigned short* be3 = wb + 129656;

  dim3 B(256);
  k_probe<<<dim3(1), B, 0, stream>>>((const unsigned*)x_raw, ei, flags);
  k_zero<<<dim3(391), B, 0, stream>>>(cnt, NNODES);

  CvtParams p;
  const int srcIdx[13] = {0, 2, 3, 4, 5, 8, 9, 10, 11, 12, 13, 14, 15};
  unsigned short* dsts[13] = {xb, Wc0, bc0, Wc1, bc1, We0, be0, We1, be1, We2, be2, We3, be3};
  const int ns[13] = {NNODES * 128, 128 * 256, 256, 256 * 256, 256,
                      128 * 40, 40, 128 * 40, 40, 256 * 40, 40, 256 * 40, 40};
  for (int i = 0; i < 13; ++i) { p.src[i] = d_in[srcIdx[i]]; p.dst[i] = dsts[i]; p.n[i] = ns[i]; }
  k_cvt<<<dim3(1024, 13), B, 0, stream>>>(p, flags);

  k_count<<<dim3(6250), B, 0, stream>>>(ei, cnt, flags);
  k_dinv<<<dim3(391), B, 0, stream>>>(cnt, dinv);
  k_psum<<<dim3(391), B, 0, stream>>>(cnt, bsum);
  k_bscan<<<dim3(1), dim3(64), 0, stream>>>(bsum, bbase, offs);
  k_offs<<<dim3(391), B, 0, stream>>>(cnt, bbase, offs, cursor);
  k_fill<<<dim3(6250), B, 0, stream>>>(ei, cursor, csr_src, csr_coef, dinv, flags);

  // layer 0: on x
  k_exit<128, true><<<dim3(782), B, 0, stream>>>(xb, We0, be0, out + 0 * 40, nullptr);
  // h1 = agg(x)
  k_agg<128><<<dim3(25000), B, 0, stream>>>(xb, hA, offs, csr_src, csr_coef, dinv);
  k_exit<128, true><<<dim3(782), B, 0, stream>>>(hA, We1, be1, out + 1 * 40, nullptr);
  k_mlp256<128><<<dim3(1563), B, 0, stream>>>(hA, Wc0, bc0, hB);
  // h2 = agg(relu(h1 Wc0 + bc0))
  k_agg<256><<<dim3(25000), B, 0, stream>>>(hB, hA, offs, csr_src, csr_coef, dinv);
  k_exit<256, true><<<dim3(782), B, 0, stream>>>(hA, We2, be2, out + 2 * 40, nullptr);
  k_mlp256<256><<<dim3(1563), B, 0, stream>>>(hA, Wc1, bc1, hB);
  // layer 3 push-through: out3 = logsoftmax(agg(hc2 @ We3) + be3)
  k_exit<256, false><<<dim3(782), B, 0, stream>>>(hB, We3, nullptr, nullptr, P);
  k_agg40<<<dim3(25000), B, 0, stream>>>(P, offs, csr_src, csr_coef, dinv, be3, out + 3 * 40);
}

// Round 6
// 1084.840 us; speedup vs baseline: 1.4193x; 1.1885x over previous
//
#include <hip/hip_runtime.h>

#define NNODES 100000
#define NEDGES 1600000

typedef __attribute__((ext_vector_type(8))) short bf16x8;
typedef __attribute__((ext_vector_type(4))) float f32x4;

// ---------- bf16 helpers ----------
__device__ __forceinline__ float bf2f(unsigned v) {
  union { unsigned u; float f; } x; x.u = v << 16; return x.f;
}
__device__ __forceinline__ unsigned short f2bf(float f) {
  union { float f; unsigned u; } x; x.f = f;
  unsigned r = x.u + 0x7fffu + ((x.u >> 16) & 1u);
  return (unsigned short)(r >> 16);
}

// ---------- dtype probing ----------
__global__ void k_probe(const unsigned* __restrict__ xw, const int* __restrict__ ei,
                        int* __restrict__ flags) {
  __shared__ int cF, cI;
  if (threadIdx.x == 0) { cF = 0; cI = 0; }
  __syncthreads();
  int t = threadIdx.x;
  int hf = 0;
  for (int i = t; i < 2048; i += 256) {
    unsigned lo = xw[i] & 0xffffu;
    unsigned e = (lo >> 7) & 0xffu;
    if (e >= 0xC0u) hf++;
  }
  atomicAdd(&cF, hf);
  int hi = 0;
  if (ei[2 * t + 1] != 0) hi++;
  atomicAdd(&cI, hi);
  __syncthreads();
  if (threadIdx.x == 0) {
    flags[0] = (cF > 32) ? 1 : 0;
    flags[1] = (cI < 16) ? 1 : 0;
  }
}

__device__ __forceinline__ int edge_at(const int* __restrict__ ei, int j, int i64) {
  return i64 ? ei[2 * j] : ei[j];
}

// ---------- canonicalize float arrays to bf16 ----------
struct CvtParams {
  const void* src[13];
  unsigned short* dst[13];
  int n[13];
};

__global__ void k_cvt(CvtParams p, const int* __restrict__ flags) {
  int a = blockIdx.y;
  int n = p.n[a];
  int f32 = flags[0];
  const float* sf = (const float*)p.src[a];
  const unsigned short* sb = (const unsigned short*)p.src[a];
  unsigned short* d = p.dst[a];
  for (int i = blockIdx.x * blockDim.x + threadIdx.x; i < n; i += gridDim.x * blockDim.x) {
    d[i] = f32 ? f2bf(sf[i]) : sb[i];
  }
}

// transpose W[K,256] -> WT[256,K]
__global__ void k_transpose(const unsigned short* __restrict__ W,
                            unsigned short* __restrict__ WT, int K) {
  int idx = blockIdx.x * 256 + threadIdx.x;
  if (idx < K * 256) {
    int k = idx >> 8, c = idx & 255;
    WT[c * K + k] = W[idx];
  }
}

__global__ void k_zero(int* __restrict__ p, int n) {
  int v = blockIdx.x * blockDim.x + threadIdx.x;
  if (v < n) p[v] = 0;
}

// ---------- graph preprocessing ----------
__global__ void k_count(const int* __restrict__ ei, int* __restrict__ cnt,
                        const int* __restrict__ flags) {
  int e = blockIdx.x * blockDim.x + threadIdx.x;
  if (e < NEDGES) {
    int i64 = flags[1];
    int d = edge_at(ei, NEDGES + e, i64);
    if ((unsigned)d < NNODES) atomicAdd(&cnt[d], 1);
  }
}

__global__ void k_dinv(const int* __restrict__ cnt, float* __restrict__ dinv) {
  int v = blockIdx.x * blockDim.x + threadIdx.x;
  if (v < NNODES) dinv[v] = rsqrtf((float)cnt[v] + 1.0f);
}

// ---------- parallel scan ----------
__global__ void k_psum(const int* __restrict__ cnt, int* __restrict__ bsum) {
  __shared__ int sw[4];
  int t = threadIdx.x;
  int i = blockIdx.x * 256 + t;
  int v = (i < NNODES) ? cnt[i] : 0;
  int x = v;
#pragma unroll
  for (int o = 1; o < 64; o <<= 1) {
    int y = __shfl_up(x, o, 64);
    if ((t & 63) >= o) x += y;
  }
  if ((t & 63) == 63) sw[t >> 6] = x;
  __syncthreads();
  if (t == 0) bsum[blockIdx.x] = sw[0] + sw[1] + sw[2] + sw[3];
}

__global__ void k_bscan(const int* __restrict__ bsum, int* __restrict__ bbase,
                        int* __restrict__ offs) {
  int l = threadIdx.x;
  int base = l * 7;
  int v[7];
  int s = 0;
#pragma unroll
  for (int k = 0; k < 7; ++k) {
    int j = base + k;
    v[k] = (j < 391) ? bsum[j] : 0;
    s += v[k];
  }
  int x = s;
#pragma unroll
  for (int o = 1; o < 64; o <<= 1) {
    int y = __shfl_up(x, o, 64);
    if (l >= o) x += y;
  }
  int excl = x - s;
#pragma unroll
  for (int k = 0; k < 7; ++k) {
    int j = base + k;
    if (j < 391) bbase[j] = excl;
    excl += v[k];
  }
  if (l == 63) offs[NNODES] = x;
}

__global__ void k_offs(const int* __restrict__ cnt, const int* __restrict__ bbase,
                       int* __restrict__ offs, int* __restrict__ cursor) {
  __shared__ int sw[4], swo[4];
  int t = threadIdx.x;
  int i = blockIdx.x * 256 + t;
  int v = (i < NNODES) ? cnt[i] : 0;
  int x = v;
#pragma unroll
  for (int o = 1; o < 64; o <<= 1) {
    int y = __shfl_up(x, o, 64);
    if ((t & 63) >= o) x += y;
  }
  if ((t & 63) == 63) sw[t >> 6] = x;
  __syncthreads();
  if (t == 0) {
    int a = 0;
#pragma unroll
    for (int w = 0; w < 4; ++w) { swo[w] = a; a += sw[w]; }
  }
  __syncthreads();
  if (i < NNODES) {
    int e = bbase[blockIdx.x] + swo[t >> 6] + x - v;
    offs[i] = e;
    cursor[i] = e;
  }
}

__global__ void k_fill(const int* __restrict__ ei, int* __restrict__ cursor,
                       int* __restrict__ csr_src, float* __restrict__ csr_coef,
                       const float* __restrict__ dinv, const int* __restrict__ flags) {
  int e = blockIdx.x * blockDim.x + threadIdx.x;
  if (e < NEDGES) {
    int i64 = flags[1];
    int s = edge_at(ei, e, i64), d = edge_at(ei, NEDGES + e, i64);
    if ((unsigned)s < NNODES && (unsigned)d < NNODES) {
      int p = atomicAdd(&cursor[d], 1);
      if ((unsigned)p < NEDGES) {
        csr_src[p] = s;
        csr_coef[p] = dinv[s] * dinv[d];
      }
    }
  }
}

// ---------- aggregation: one wave per node, CSR gather, fp32 accum ----------
template <int D>
__global__ __launch_bounds__(256) void k_agg(
    const unsigned short* __restrict__ hin, unsigned short* __restrict__ hout,
    const int* __restrict__ offs, const int* __restrict__ csr_src,
    const float* __restrict__ csr_coef, const float* __restrict__ dinv) {
  constexpr int PER = D / 64;
  int w = (blockIdx.x * 256 + threadIdx.x) >> 6;
  int lane = threadIdx.x & 63;
  if (w >= NNODES) return;
  float dv = dinv[w];
  float acc[PER];
  size_t base = (size_t)w * D + lane * PER;
  if (PER == 4) {
    uint2 u = *(const uint2*)(hin + base);
    acc[0] = bf2f(u.x & 0xffffu) * dv * dv;
    acc[1] = bf2f(u.x >> 16) * dv * dv;
    acc[2] = bf2f(u.y & 0xffffu) * dv * dv;
    acc[3] = bf2f(u.y >> 16) * dv * dv;
  } else {
    unsigned u = *(const unsigned*)(hin + base);
    acc[0] = bf2f(u & 0xffffu) * dv * dv;
    acc[1] = bf2f(u >> 16) * dv * dv;
  }
  int b = offs[w], e = offs[w + 1];
  for (int i = b; i < e; ++i) {
    int s = csr_src[i];
    s = ((unsigned)s < NNODES) ? s : 0;
    float c = csr_coef[i];
    size_t sb = (size_t)s * D + lane * PER;
    if (PER == 4) {
      uint2 u = *(const uint2*)(hin + sb);
      acc[0] += c * bf2f(u.x & 0xffffu);
      acc[1] += c * bf2f(u.x >> 16);
      acc[2] += c * bf2f(u.y & 0xffffu);
      acc[3] += c * bf2f(u.y >> 16);
    } else {
      unsigned u = *(const unsigned*)(hin + sb);
      acc[0] += c * bf2f(u & 0xffffu);
      acc[1] += c * bf2f(u >> 16);
    }
  }
  if (PER == 4) {
    uint2 o;
    o.x = (unsigned)f2bf(acc[0]) | ((unsigned)f2bf(acc[1]) << 16);
    o.y = (unsigned)f2bf(acc[2]) | ((unsigned)f2bf(acc[3]) << 16);
    *(uint2*)(hout + base) = o;
  } else {
    *(unsigned*)(hout + base) =
        (unsigned)f2bf(acc[0]) | ((unsigned)f2bf(acc[1]) << 16);
  }
}

// ---------- width-40 aggregation + bias + log_softmax (layer 3) ----------
__global__ __launch_bounds__(256) void k_agg40(
    const unsigned short* __restrict__ P, const int* __restrict__ offs,
    const int* __restrict__ csr_src, const float* __restrict__ csr_coef,
    const float* __restrict__ dinv, const unsigned short* __restrict__ bias,
    float* __restrict__ outp) {
  int w = (blockIdx.x * 256 + threadIdx.x) >> 6;
  int lane = threadIdx.x & 63;
  if (w >= NNODES) return;
  float dv = dinv[w];
  float a0 = 0.f, a1 = 0.f;
  if (lane < 20) {
    unsigned u = *(const unsigned*)(P + (size_t)w * 40 + lane * 2);
    a0 = bf2f(u & 0xffffu) * dv * dv;
    a1 = bf2f(u >> 16) * dv * dv;
  }
  int b = offs[w], e = offs[w + 1];
  for (int i = b; i < e; ++i) {
    int s = csr_src[i];
    s = ((unsigned)s < NNODES) ? s : 0;
    float c = csr_coef[i];
    if (lane < 20) {
      unsigned u = *(const unsigned*)(P + (size_t)s * 40 + lane * 2);
      a0 += c * bf2f(u & 0xffffu);
      a1 += c * bf2f(u >> 16);
    }
  }
  if (lane < 20) {
    a0 += bf2f((unsigned)bias[lane * 2]);
    a1 += bf2f((unsigned)bias[lane * 2 + 1]);
  }
  float m = (lane < 20) ? fmaxf(a0, a1) : -1e30f;
#pragma unroll
  for (int o = 16; o > 0; o >>= 1) m = fmaxf(m, __shfl_xor(m, o, 32));
  float ss = (lane < 20) ? (expf(a0 - m) + expf(a1 - m)) : 0.f;
#pragma unroll
  for (int o = 16; o > 0; o >>= 1) ss += __shfl_xor(ss, o, 32);
  float ls = logf(ss) + m;
  if (lane < 20) {
    float2 o2;
    o2.x = a0 - ls;
    o2.y = a1 - ls;
    *(float2*)(outp + (size_t)w * 160 + lane * 2) = o2;
  }
}

// ---------- MFMA continue GEMM: out = relu(A[N,K] @ W[K,256] + b) ----------
// WT is W transposed: [256 cols][K]. 128x128 tile/block, 4 waves 2x2,
// each wave 64x64 via 4x4 mfma_f32_16x16x32_bf16. LDS rows padded to 40
// halfwords (2-way bank aliasing = free).
template <int K>
__global__ __launch_bounds__(256) void k_mlp_mfma(
    const unsigned short* __restrict__ A, const unsigned short* __restrict__ WT,
    const unsigned short* __restrict__ bias, unsigned short* __restrict__ out) {
  __shared__ short As[128 * 40];
  __shared__ short Bs[128 * 40];
  const int t = threadIdx.x;
  const int lane = t & 63, wv = t >> 6;
  const int m0 = blockIdx.x * 128;
  const int c0 = blockIdx.y * 128;
  const int mw = (wv >> 1) * 64, nw = (wv & 1) * 64;
  const int lr = lane & 15, lq = lane >> 4;

  f32x4 acc[4][4];
#pragma unroll
  for (int i = 0; i < 4; ++i)
#pragma unroll
    for (int j = 0; j < 4; ++j) acc[i][j] = (f32x4)0.f;

  for (int kc = 0; kc < K; kc += 32) {
    __syncthreads();
#pragma unroll
    for (int it = 0; it < 2; ++it) {
      int idx = t + it * 256;
      int row = idx >> 2, seg = idx & 3;
      uint4 u = make_uint4(0, 0, 0, 0);
      int gr = m0 + row;
      if (gr < NNODES) u = *(const uint4*)(A + (size_t)gr * K + kc + seg * 8);
      *(uint4*)&As[row * 40 + seg * 8] = u;
      uint4 v = *(const uint4*)(WT + (size_t)(c0 + row) * K + kc + seg * 8);
      *(uint4*)&Bs[row * 40 + seg * 8] = v;
    }
    __syncthreads();
    bf16x8 af[4], bfr[4];
#pragma unroll
    for (int i = 0; i < 4; ++i)
      af[i] = *(const bf16x8*)&As[(mw + 16 * i + lr) * 40 + lq * 8];
#pragma unroll
    for (int j = 0; j < 4; ++j)
      bfr[j] = *(const bf16x8*)&Bs[(nw + 16 * j + lr) * 40 + lq * 8];
#pragma unroll
    for (int i = 0; i < 4; ++i)
#pragma unroll
      for (int j = 0; j < 4; ++j)
        acc[i][j] = __builtin_amdgcn_mfma_f32_16x16x32_bf16(af[i], bfr[j], acc[i][j], 0, 0, 0);
  }

  float bv[4];
#pragma unroll
  for (int j = 0; j < 4; ++j) bv[j] = bf2f((unsigned)bias[c0 + nw + 16 * j + lr]);
#pragma unroll
  for (int i = 0; i < 4; ++i) {
    int rbase = m0 + mw + 16 * i + lq * 4;
#pragma unroll
    for (int r = 0; r < 4; ++r) {
      int row = rbase + r;
      if (row < NNODES) {
#pragma unroll
        for (int j = 0; j < 4; ++j) {
          int col = c0 + nw + 16 * j + lr;
          float v = fmaxf(acc[i][j][r] + bv[j], 0.f);
          out[(size_t)row * 256 + col] = f2bf(v);
        }
      }
    }
  }
}

// ---------- exit GEMM core (shared by softmax-out and P-out variants) ----------
template <int K, bool SOFTMAX>
__global__ __launch_bounds__(256) void k_exit(
    const unsigned short* __restrict__ A, const unsigned short* __restrict__ W,
    const unsigned short* __restrict__ bias, float* __restrict__ outp,
    unsigned short* __restrict__ Pout) {
  __shared__ float sA[16][128];
  __shared__ float sW[16][48];
  __shared__ float sO[128][41];
  const int t = threadIdx.x;
  const int m0 = blockIdx.x * 128;
  const int ng = t >> 2, jg = t & 3;
  const int n0 = ng * 2, j0 = jg * 10, jw = jg * 12;
  float acc[2][10];
#pragma unroll
  for (int i = 0; i < 2; ++i)
#pragma unroll
    for (int j = 0; j < 10; ++j) acc[i][j] = 0.f;

  for (int kc = 0; kc < K / 16; ++kc) {
    __syncthreads();
    {
      int r = t >> 1, half = t & 1;
      uint4 u = make_uint4(0, 0, 0, 0);
      int row = m0 + r;
      if (row < NNODES) u = *(const uint4*)(A + (size_t)row * K + kc * 16 + half * 8);
      int kb = half * 8;
      sA[kb + 0][r] = bf2f(u.x & 0xffffu);
      sA[kb + 1][r] = bf2f(u.x >> 16);
      sA[kb + 2][r] = bf2f(u.y & 0xffffu);
      sA[kb + 3][r] = bf2f(u.y >> 16);
      sA[kb + 4][r] = bf2f(u.z & 0xffffu);
      sA[kb + 5][r] = bf2f(u.z >> 16);
      sA[kb + 6][r] = bf2f(u.w & 0xffffu);
      sA[kb + 7][r] = bf2f(u.w >> 16);
    }
    for (int e = t; e < 640; e += 256) {
      int kl = e / 40, j = e % 40;
      sW[kl][(j / 10) * 12 + (j % 10)] = bf2f((unsigned)W[(size_t)(kc * 16 + kl) * 40 + j]);
    }
    __syncthreads();
#pragma unroll
    for (int k = 0; k < 16; ++k) {
      float2 a = *(const float2*)&sA[k][n0];
      float4 w0 = *(const float4*)&sW[k][jw];
      float4 w1 = *(const float4*)&sW[k][jw + 4];
      float2 w2 = *(const float2*)&sW[k][jw + 8];
      float wv[10] = {w0.x, w0.y, w0.z, w0.w, w1.x, w1.y, w1.z, w1.w, w2.x, w2.y};
#pragma unroll
      for (int j = 0; j < 10; ++j) {
        acc[0][j] += a.x * wv[j];
        acc[1][j] += a.y * wv[j];
      }
    }
  }

  if (SOFTMAX) {
    float bv[10];
#pragma unroll
    for (int j = 0; j < 10; ++j) bv[j] = bf2f((unsigned)bias[j0 + j]);
    __syncthreads();
#pragma unroll
    for (int i = 0; i < 2; ++i)
#pragma unroll
      for (int j = 0; j < 10; ++j) sO[n0 + i][j0 + j] = acc[i][j] + bv[j];
    __syncthreads();
    if (t < 128) {
      int row = m0 + t;
      if (row < NNODES) {
        float m = -1e30f;
#pragma unroll
        for (int j = 0; j < 40; ++j) m = fmaxf(m, sO[t][j]);
        float ssum = 0.f;
#pragma unroll
        for (int j = 0; j < 40; ++j) ssum += expf(sO[t][j] - m);
        float ls = logf(ssum) + m;
#pragma unroll
        for (int j = 0; j < 40; ++j)
          outp[(size_t)row * 160 + j] = sO[t][j] - ls;
      }
    }
  } else {
#pragma unroll
    for (int i = 0; i < 2; ++i) {
      int row = m0 + n0 + i;
      if (row < NNODES) {
#pragma unroll
        for (int j = 0; j < 10; j += 2) {
          unsigned o = (unsigned)f2bf(acc[i][j]) | ((unsigned)f2bf(acc[i][j + 1]) << 16);
          *(unsigned*)(Pout + (size_t)row * 40 + j0 + j) = o;
        }
      }
    }
  }
}

// ---------- launch ----------
extern "C" void kernel_launch(void* const* d_in, const int* in_sizes, int n_in,
                              void* d_out, int out_size, void* d_ws, size_t ws_size,
                              hipStream_t stream) {
  const void* x_raw   = d_in[0];
  const int* ei       = (const int*)d_in[1];
  float* out          = (float*)d_out;

  char* ws = (char*)d_ws;
  int*   flags    = (int*)(ws + 0);
  int*   bsum     = (int*)(ws + 1024);
  int*   bbase    = (int*)(ws + 2816);
  int*   cnt      = (int*)(ws + 8192);
  int*   offs     = (int*)(ws + 524288);
  int*   cursor   = (int*)(ws + 1048576);
  float* dinv     = (float*)(ws + 1572864);
  int*   csr_src  = (int*)(ws + 2097152);       // 6.4 MB
  float* csr_coef = (float*)(ws + 9437184);     // 6.4 MB
  unsigned short* xb = (unsigned short*)(ws + 16777216);   // N*128 bf16 (reused as P later)
  unsigned short* wb = (unsigned short*)(ws + 45088768);   // weights
  unsigned short* hA = (unsigned short*)(ws + 48234496);   // N*256 bf16
  unsigned short* hB = (unsigned short*)(ws + 100663296);  // N*256 bf16
  unsigned short* P  = xb;

  unsigned short* Wc0 = wb + 0;
  unsigned short* bc0 = wb + 32768;
  unsigned short* Wc1 = wb + 33024;
  unsigned short* bc1 = wb + 98560;
  unsigned short* We0 = wb + 98816;
  unsigned short* be0 = wb + 103936;
  unsigned short* We1 = wb + 103976;
  unsigned short* be1 = wb + 109096;
  unsigned short* We2 = wb + 109136;
  unsigned short* be2 = wb + 119376;
  unsigned short* We3 = wb + 119416;
  unsigned short* be3 = wb + 129656;
  unsigned short* WTc0 = wb + 131072;  // 256 x 128
  unsigned short* WTc1 = wb + 163840;  // 256 x 256

  dim3 B(256);
  k_probe<<<dim3(1), B, 0, stream>>>((const unsigned*)x_raw, ei, flags);
  k_zero<<<dim3(391), B, 0, stream>>>(cnt, NNODES);

  CvtParams p;
  const int srcIdx[13] = {0, 2, 3, 4, 5, 8, 9, 10, 11, 12, 13, 14, 15};
  unsigned short* dsts[13] = {xb, Wc0, bc0, Wc1, bc1, We0, be0, We1, be1, We2, be2, We3, be3};
  const int ns[13] = {NNODES * 128, 128 * 256, 256, 256 * 256, 256,
                      128 * 40, 40, 128 * 40, 40, 256 * 40, 40, 256 * 40, 40};
  for (int i = 0; i < 13; ++i) { p.src[i] = d_in[srcIdx[i]]; p.dst[i] = dsts[i]; p.n[i] = ns[i]; }
  k_cvt<<<dim3(1024, 13), B, 0, stream>>>(p, flags);
  k_transpose<<<dim3(128), B, 0, stream>>>(Wc0, WTc0, 128);
  k_transpose<<<dim3(256), B, 0, stream>>>(Wc1, WTc1, 256);

  k_count<<<dim3(6250), B, 0, stream>>>(ei, cnt, flags);
  k_dinv<<<dim3(391), B, 0, stream>>>(cnt, dinv);
  k_psum<<<dim3(391), B, 0, stream>>>(cnt, bsum);
  k_bscan<<<dim3(1), dim3(64), 0, stream>>>(bsum, bbase, offs);
  k_offs<<<dim3(391), B, 0, stream>>>(cnt, bbase, offs, cursor);
  k_fill<<<dim3(6250), B, 0, stream>>>(ei, cursor, csr_src, csr_coef, dinv, flags);

  // layer 0: on x
  k_exit<128, true><<<dim3(782), B, 0, stream>>>(xb, We0, be0, out + 0 * 40, nullptr);
  // h1 = agg(x)
  k_agg<128><<<dim3(25000), B, 0, stream>>>(xb, hA, offs, csr_src, csr_coef, dinv);
  k_exit<128, true><<<dim3(782), B, 0, stream>>>(hA, We1, be1, out + 1 * 40, nullptr);
  k_mlp_mfma<128><<<dim3(782, 2), B, 0, stream>>>(hA, WTc0, bc0, hB);
  // h2 = agg(relu(h1 Wc0 + bc0))
  k_agg<256><<<dim3(25000), B, 0, stream>>>(hB, hA, offs, csr_src, csr_coef, dinv);
  k_exit<256, true><<<dim3(782), B, 0, stream>>>(hA, We2, be2, out + 2 * 40, nullptr);
  k_mlp_mfma<256><<<dim3(782, 2), B, 0, stream>>>(hA, WTc1, bc1, hB);
  // layer 3 push-through: out3 = logsoftmax(agg(hc2 @ We3) + be3)
  k_exit<256, false><<<dim3(782), B, 0, stream>>>(hB, We3, nullptr, nullptr, P);
  k_agg40<<<dim3(25000), B, 0, stream>>>(P, offs, csr_src, csr_coef, dinv, be3, out + 3 * 40);
}

// Round 7
// 742.570 us; speedup vs baseline: 2.0736x; 1.4609x over previous
//
#include <hip/hip_runtime.h>

#define NNODES 100000
#define NEDGES 1600000

typedef __attribute__((ext_vector_type(8))) short bf16x8;
typedef __attribute__((ext_vector_type(4))) float f32x4;

// ---------- bf16 helpers ----------
__device__ __forceinline__ float bf2f(unsigned v) {
  union { unsigned u; float f; } x; x.u = v << 16; return x.f;
}
__device__ __forceinline__ unsigned short f2bf(float f) {
  union { float f; unsigned u; } x; x.f = f;
  unsigned r = x.u + 0x7fffu + ((x.u >> 16) & 1u);
  return (unsigned short)(r >> 16);
}

// ---------- dtype probing ----------
__global__ void k_probe(const unsigned* __restrict__ xw, const int* __restrict__ ei,
                        int* __restrict__ flags) {
  __shared__ int cF, cI;
  if (threadIdx.x == 0) { cF = 0; cI = 0; }
  __syncthreads();
  int t = threadIdx.x;
  int hf = 0;
  for (int i = t; i < 2048; i += 256) {
    unsigned lo = xw[i] & 0xffffu;
    unsigned e = (lo >> 7) & 0xffu;
    if (e >= 0xC0u) hf++;
  }
  atomicAdd(&cF, hf);
  int hi = 0;
  if (ei[2 * t + 1] != 0) hi++;
  atomicAdd(&cI, hi);
  __syncthreads();
  if (threadIdx.x == 0) {
    flags[0] = (cF > 32) ? 1 : 0;
    flags[1] = (cI < 16) ? 1 : 0;
  }
}

__device__ __forceinline__ int edge_at(const int* __restrict__ ei, int j, int i64) {
  return i64 ? ei[2 * j] : ei[j];
}

// ---------- canonicalize float arrays to bf16 ----------
struct CvtParams {
  const void* src[13];
  unsigned short* dst[13];
  int n[13];
};

__global__ void k_cvt(CvtParams p, const int* __restrict__ flags) {
  int a = blockIdx.y;
  int n = p.n[a];
  int f32 = flags[0];
  const float* sf = (const float*)p.src[a];
  const unsigned short* sb = (const unsigned short*)p.src[a];
  unsigned short* d = p.dst[a];
  for (int i = blockIdx.x * blockDim.x + threadIdx.x; i < n; i += gridDim.x * blockDim.x) {
    d[i] = f32 ? f2bf(sf[i]) : sb[i];
  }
}

// transpose W[K,256] -> WT[256,K]
__global__ void k_transpose(const unsigned short* __restrict__ W,
                            unsigned short* __restrict__ WT, int K) {
  int idx = blockIdx.x * 256 + threadIdx.x;
  if (idx < K * 256) {
    int k = idx >> 8, c = idx & 255;
    WT[c * K + k] = W[idx];
  }
}

// transpose W[K,40] -> WT[48,K], rows 40..47 zero
template <int K>
__global__ void k_transpose40(const unsigned short* __restrict__ W,
                              unsigned short* __restrict__ WT) {
  int idx = blockIdx.x * 256 + threadIdx.x;
  if (idx < 48 * K) {
    int c = idx / K, k = idx % K;
    WT[idx] = (c < 40) ? W[k * 40 + c] : (unsigned short)0;
  }
}

__global__ void k_zero(int* __restrict__ p, int n) {
  int v = blockIdx.x * blockDim.x + threadIdx.x;
  if (v < n) p[v] = 0;
}

// ---------- graph preprocessing ----------
__global__ void k_count(const int* __restrict__ ei, int* __restrict__ cnt,
                        const int* __restrict__ flags) {
  int e = blockIdx.x * blockDim.x + threadIdx.x;
  if (e < NEDGES) {
    int i64 = flags[1];
    int d = edge_at(ei, NEDGES + e, i64);
    if ((unsigned)d < NNODES) atomicAdd(&cnt[d], 1);
  }
}

__global__ void k_dinv(const int* __restrict__ cnt, float* __restrict__ dinv) {
  int v = blockIdx.x * blockDim.x + threadIdx.x;
  if (v < NNODES) dinv[v] = rsqrtf((float)cnt[v] + 1.0f);
}

// ---------- parallel scan ----------
__global__ void k_psum(const int* __restrict__ cnt, int* __restrict__ bsum) {
  __shared__ int sw[4];
  int t = threadIdx.x;
  int i = blockIdx.x * 256 + t;
  int v = (i < NNODES) ? cnt[i] : 0;
  int x = v;
#pragma unroll
  for (int o = 1; o < 64; o <<= 1) {
    int y = __shfl_up(x, o, 64);
    if ((t & 63) >= o) x += y;
  }
  if ((t & 63) == 63) sw[t >> 6] = x;
  __syncthreads();
  if (t == 0) bsum[blockIdx.x] = sw[0] + sw[1] + sw[2] + sw[3];
}

__global__ void k_bscan(const int* __restrict__ bsum, int* __restrict__ bbase,
                        int* __restrict__ offs) {
  int l = threadIdx.x;
  int base = l * 7;
  int v[7];
  int s = 0;
#pragma unroll
  for (int k = 0; k < 7; ++k) {
    int j = base + k;
    v[k] = (j < 391) ? bsum[j] : 0;
    s += v[k];
  }
  int x = s;
#pragma unroll
  for (int o = 1; o < 64; o <<= 1) {
    int y = __shfl_up(x, o, 64);
    if (l >= o) x += y;
  }
  int excl = x - s;
#pragma unroll
  for (int k = 0; k < 7; ++k) {
    int j = base + k;
    if (j < 391) bbase[j] = excl;
    excl += v[k];
  }
  if (l == 63) offs[NNODES] = x;
}

__global__ void k_offs(const int* __restrict__ cnt, const int* __restrict__ bbase,
                       int* __restrict__ offs, int* __restrict__ cursor) {
  __shared__ int sw[4], swo[4];
  int t = threadIdx.x;
  int i = blockIdx.x * 256 + t;
  int v = (i < NNODES) ? cnt[i] : 0;
  int x = v;
#pragma unroll
  for (int o = 1; o < 64; o <<= 1) {
    int y = __shfl_up(x, o, 64);
    if ((t & 63) >= o) x += y;
  }
  if ((t & 63) == 63) sw[t >> 6] = x;
  __syncthreads();
  if (t == 0) {
    int a = 0;
#pragma unroll
    for (int w = 0; w < 4; ++w) { swo[w] = a; a += sw[w]; }
  }
  __syncthreads();
  if (i < NNODES) {
    int e = bbase[blockIdx.x] + swo[t >> 6] + x - v;
    offs[i] = e;
    cursor[i] = e;
  }
}

// fill combined CSR records: {src, coef} per edge (8 B)
__global__ void k_fill(const int* __restrict__ ei, int* __restrict__ cursor,
                       uint2* __restrict__ csr_sc, const float* __restrict__ dinv,
                       const int* __restrict__ flags) {
  int e = blockIdx.x * blockDim.x + threadIdx.x;
  if (e < NEDGES) {
    int i64 = flags[1];
    int s = edge_at(ei, e, i64), d = edge_at(ei, NEDGES + e, i64);
    if ((unsigned)s < NNODES && (unsigned)d < NNODES) {
      int p = atomicAdd(&cursor[d], 1);
      if ((unsigned)p < NEDGES) {
        float c = dinv[s] * dinv[d];
        uint2 rec;
        rec.x = (unsigned)s;
        union { float f; unsigned u; } cu; cu.f = c;
        rec.y = cu.u;
        csr_sc[p] = rec;
      }
    }
  }
}

__device__ __forceinline__ float u2f(unsigned u) {
  union { unsigned u; float f; } x; x.u = u; return x.f;
}

// ---------- aggregation: one wave per node, 4-deep pipelined CSR gather ----------
template <int D>
__global__ __launch_bounds__(256) void k_agg(
    const unsigned short* __restrict__ hin, unsigned short* __restrict__ hout,
    const int* __restrict__ offs, const uint2* __restrict__ csr_sc,
    const float* __restrict__ dinv) {
  constexpr int PER = D / 64;
  int w = (blockIdx.x * 256 + threadIdx.x) >> 6;
  int lane = threadIdx.x & 63;
  if (w >= NNODES) return;
  float dv = dinv[w];
  float acc[PER];
  size_t base = (size_t)w * D + lane * PER;
  if (PER == 4) {
    uint2 u = *(const uint2*)(hin + base);
    acc[0] = bf2f(u.x & 0xffffu) * dv * dv;
    acc[1] = bf2f(u.x >> 16) * dv * dv;
    acc[2] = bf2f(u.y & 0xffffu) * dv * dv;
    acc[3] = bf2f(u.y >> 16) * dv * dv;
  } else {
    unsigned u = *(const unsigned*)(hin + base);
    acc[0] = bf2f(u & 0xffffu) * dv * dv;
    acc[1] = bf2f(u >> 16) * dv * dv;
  }
  int b = offs[w], e = offs[w + 1];
  int i = b;
  const unsigned lim = NNODES - 1;
  for (; i + 4 <= e; i += 4) {
    uint2 m0 = csr_sc[i], m1 = csr_sc[i + 1], m2 = csr_sc[i + 2], m3 = csr_sc[i + 3];
    const unsigned short* p0 = hin + (size_t)(m0.x < lim ? m0.x : lim) * D + lane * PER;
    const unsigned short* p1 = hin + (size_t)(m1.x < lim ? m1.x : lim) * D + lane * PER;
    const unsigned short* p2 = hin + (size_t)(m2.x < lim ? m2.x : lim) * D + lane * PER;
    const unsigned short* p3 = hin + (size_t)(m3.x < lim ? m3.x : lim) * D + lane * PER;
    if (PER == 4) {
      uint2 u0 = *(const uint2*)p0;
      uint2 u1 = *(const uint2*)p1;
      uint2 u2 = *(const uint2*)p2;
      uint2 u3 = *(const uint2*)p3;
      float c0 = u2f(m0.y), c1 = u2f(m1.y), c2 = u2f(m2.y), c3 = u2f(m3.y);
      acc[0] += c0 * bf2f(u0.x & 0xffffu);
      acc[1] += c0 * bf2f(u0.x >> 16);
      acc[2] += c0 * bf2f(u0.y & 0xffffu);
      acc[3] += c0 * bf2f(u0.y >> 16);
      acc[0] += c1 * bf2f(u1.x & 0xffffu);
      acc[1] += c1 * bf2f(u1.x >> 16);
      acc[2] += c1 * bf2f(u1.y & 0xffffu);
      acc[3] += c1 * bf2f(u1.y >> 16);
      acc[0] += c2 * bf2f(u2.x & 0xffffu);
      acc[1] += c2 * bf2f(u2.x >> 16);
      acc[2] += c2 * bf2f(u2.y & 0xffffu);
      acc[3] += c2 * bf2f(u2.y >> 16);
      acc[0] += c3 * bf2f(u3.x & 0xffffu);
      acc[1] += c3 * bf2f(u3.x >> 16);
      acc[2] += c3 * bf2f(u3.y & 0xffffu);
      acc[3] += c3 * bf2f(u3.y >> 16);
    } else {
      unsigned u0 = *(const unsigned*)p0;
      unsigned u1 = *(const unsigned*)p1;
      unsigned u2 = *(const unsigned*)p2;
      unsigned u3 = *(const unsigned*)p3;
      float c0 = u2f(m0.y), c1 = u2f(m1.y), c2 = u2f(m2.y), c3 = u2f(m3.y);
      acc[0] += c0 * bf2f(u0 & 0xffffu);
      acc[1] += c0 * bf2f(u0 >> 16);
      acc[0] += c1 * bf2f(u1 & 0xffffu);
      acc[1] += c1 * bf2f(u1 >> 16);
      acc[0] += c2 * bf2f(u2 & 0xffffu);
      acc[1] += c2 * bf2f(u2 >> 16);
      acc[0] += c3 * bf2f(u3 & 0xffffu);
      acc[1] += c3 * bf2f(u3 >> 16);
    }
  }
  for (; i < e; ++i) {
    uint2 m = csr_sc[i];
    float c = u2f(m.y);
    size_t sb = (size_t)(m.x < lim ? m.x : lim) * D + lane * PER;
    if (PER == 4) {
      uint2 u = *(const uint2*)(hin + sb);
      acc[0] += c * bf2f(u.x & 0xffffu);
      acc[1] += c * bf2f(u.x >> 16);
      acc[2] += c * bf2f(u.y & 0xffffu);
      acc[3] += c * bf2f(u.y >> 16);
    } else {
      unsigned u = *(const unsigned*)(hin + sb);
      acc[0] += c * bf2f(u & 0xffffu);
      acc[1] += c * bf2f(u >> 16);
    }
  }
  if (PER == 4) {
    uint2 o;
    o.x = (unsigned)f2bf(acc[0]) | ((unsigned)f2bf(acc[1]) << 16);
    o.y = (unsigned)f2bf(acc[2]) | ((unsigned)f2bf(acc[3]) << 16);
    *(uint2*)(hout + base) = o;
  } else {
    *(unsigned*)(hout + base) =
        (unsigned)f2bf(acc[0]) | ((unsigned)f2bf(acc[1]) << 16);
  }
}

// ---------- width-40 aggregation + bias + log_softmax (layer 3) ----------
__global__ __launch_bounds__(256) void k_agg40(
    const unsigned short* __restrict__ P, const int* __restrict__ offs,
    const uint2* __restrict__ csr_sc, const float* __restrict__ dinv,
    const unsigned short* __restrict__ bias, float* __restrict__ outp) {
  int w = (blockIdx.x * 256 + threadIdx.x) >> 6;
  int lane = threadIdx.x & 63;
  if (w >= NNODES) return;
  float dv = dinv[w];
  float a0 = 0.f, a1 = 0.f;
  const unsigned lim = NNODES - 1;
  if (lane < 20) {
    unsigned u = *(const unsigned*)(P + (size_t)w * 40 + lane * 2);
    a0 = bf2f(u & 0xffffu) * dv * dv;
    a1 = bf2f(u >> 16) * dv * dv;
  }
  int b = offs[w], e = offs[w + 1];
  int i = b;
  for (; i + 4 <= e; i += 4) {
    uint2 m0 = csr_sc[i], m1 = csr_sc[i + 1], m2 = csr_sc[i + 2], m3 = csr_sc[i + 3];
    if (lane < 20) {
      unsigned u0 = *(const unsigned*)(P + (size_t)(m0.x < lim ? m0.x : lim) * 40 + lane * 2);
      unsigned u1 = *(const unsigned*)(P + (size_t)(m1.x < lim ? m1.x : lim) * 40 + lane * 2);
      unsigned u2 = *(const unsigned*)(P + (size_t)(m2.x < lim ? m2.x : lim) * 40 + lane * 2);
      unsigned u3 = *(const unsigned*)(P + (size_t)(m3.x < lim ? m3.x : lim) * 40 + lane * 2);
      float c0 = u2f(m0.y), c1 = u2f(m1.y), c2 = u2f(m2.y), c3 = u2f(m3.y);
      a0 += c0 * bf2f(u0 & 0xffffu);
      a1 += c0 * bf2f(u0 >> 16);
      a0 += c1 * bf2f(u1 & 0xffffu);
      a1 += c1 * bf2f(u1 >> 16);
      a0 += c2 * bf2f(u2 & 0xffffu);
      a1 += c2 * bf2f(u2 >> 16);
      a0 += c3 * bf2f(u3 & 0xffffu);
      a1 += c3 * bf2f(u3 >> 16);
    }
  }
  for (; i < e; ++i) {
    uint2 m = csr_sc[i];
    if (lane < 20) {
      unsigned u = *(const unsigned*)(P + (size_t)(m.x < lim ? m.x : lim) * 40 + lane * 2);
      float c = u2f(m.y);
      a0 += c * bf2f(u & 0xffffu);
      a1 += c * bf2f(u >> 16);
    }
  }
  if (lane < 20) {
    a0 += bf2f((unsigned)bias[lane * 2]);
    a1 += bf2f((unsigned)bias[lane * 2 + 1]);
  }
  float m = (lane < 20) ? fmaxf(a0, a1) : -1e30f;
#pragma unroll
  for (int o = 16; o > 0; o >>= 1) m = fmaxf(m, __shfl_xor(m, o, 32));
  float ss = (lane < 20) ? (expf(a0 - m) + expf(a1 - m)) : 0.f;
#pragma unroll
  for (int o = 16; o > 0; o >>= 1) ss += __shfl_xor(ss, o, 32);
  float ls = logf(ss) + m;
  if (lane < 20) {
    float2 o2;
    o2.x = a0 - ls;
    o2.y = a1 - ls;
    *(float2*)(outp + (size_t)w * 160 + lane * 2) = o2;
  }
}

// ---------- MFMA continue GEMM: out = relu(A[N,K] @ W[K,256] + b) ----------
template <int K>
__global__ __launch_bounds__(256) void k_mlp_mfma(
    const unsigned short* __restrict__ A, const unsigned short* __restrict__ WT,
    const unsigned short* __restrict__ bias, unsigned short* __restrict__ out) {
  __shared__ short As[128 * 40];
  __shared__ short Bs[128 * 40];
  const int t = threadIdx.x;
  const int lane = t & 63, wv = t >> 6;
  const int m0 = blockIdx.x * 128;
  const int c0 = blockIdx.y * 128;
  const int mw = (wv >> 1) * 64, nw = (wv & 1) * 64;
  const int lr = lane & 15, lq = lane >> 4;

  f32x4 acc[4][4];
#pragma unroll
  for (int i = 0; i < 4; ++i)
#pragma unroll
    for (int j = 0; j < 4; ++j) acc[i][j] = (f32x4)0.f;

  for (int kc = 0; kc < K; kc += 32) {
    __syncthreads();
#pragma unroll
    for (int it = 0; it < 2; ++it) {
      int idx = t + it * 256;
      int row = idx >> 2, seg = idx & 3;
      uint4 u = make_uint4(0, 0, 0, 0);
      int gr = m0 + row;
      if (gr < NNODES) u = *(const uint4*)(A + (size_t)gr * K + kc + seg * 8);
      *(uint4*)&As[row * 40 + seg * 8] = u;
      uint4 v = *(const uint4*)(WT + (size_t)(c0 + row) * K + kc + seg * 8);
      *(uint4*)&Bs[row * 40 + seg * 8] = v;
    }
    __syncthreads();
    bf16x8 af[4], bfr[4];
#pragma unroll
    for (int i = 0; i < 4; ++i)
      af[i] = *(const bf16x8*)&As[(mw + 16 * i + lr) * 40 + lq * 8];
#pragma unroll
    for (int j = 0; j < 4; ++j)
      bfr[j] = *(const bf16x8*)&Bs[(nw + 16 * j + lr) * 40 + lq * 8];
#pragma unroll
    for (int i = 0; i < 4; ++i)
#pragma unroll
      for (int j = 0; j < 4; ++j)
        acc[i][j] = __builtin_amdgcn_mfma_f32_16x16x32_bf16(af[i], bfr[j], acc[i][j], 0, 0, 0);
  }

  float bv[4];
#pragma unroll
  for (int j = 0; j < 4; ++j) bv[j] = bf2f((unsigned)bias[c0 + nw + 16 * j + lr]);
#pragma unroll
  for (int i = 0; i < 4; ++i) {
    int rbase = m0 + mw + 16 * i + lq * 4;
#pragma unroll
    for (int r = 0; r < 4; ++r) {
      int row = rbase + r;
      if (row < NNODES) {
#pragma unroll
        for (int j = 0; j < 4; ++j) {
          int col = c0 + nw + 16 * j + lr;
          float v = fmaxf(acc[i][j][r] + bv[j], 0.f);
          out[(size_t)row * 256 + col] = f2bf(v);
        }
      }
    }
  }
}

// ---------- MFMA exit GEMM (+ optional fused log_softmax) ----------
// WT: [48][K] (cols of We, rows 40..47 zero). 256-row tile, 4 waves x 64 rows,
// 3 col-tiles of 16. C/D: col=lane&15, row=quad*4+reg (quad-uniform rows).
template <int K, bool SOFTMAX>
__global__ __launch_bounds__(256) void k_exit_mfma(
    const unsigned short* __restrict__ A, const unsigned short* __restrict__ WT,
    const unsigned short* __restrict__ bias, float* __restrict__ outp,
    unsigned short* __restrict__ Pout) {
  __shared__ short As[256 * 40];
  __shared__ short Bs[48 * 40];
  const int t = threadIdx.x;
  const int lane = t & 63, wv = t >> 6;
  const int m0 = blockIdx.x * 256;
  const int mw = wv * 64;
  const int lr = lane & 15, lq = lane >> 4;

  f32x4 acc[4][3];
#pragma unroll
  for (int i = 0; i < 4; ++i)
#pragma unroll
    for (int j = 0; j < 3; ++j) acc[i][j] = (f32x4)0.f;

  for (int kc = 0; kc < K; kc += 32) {
    __syncthreads();
#pragma unroll
    for (int it = 0; it < 4; ++it) {
      int idx = t + it * 256;
      int row = idx >> 2, seg = idx & 3;
      uint4 u = make_uint4(0, 0, 0, 0);
      int gr = m0 + row;
      if (gr < NNODES) u = *(const uint4*)(A + (size_t)gr * K + kc + seg * 8);
      *(uint4*)&As[row * 40 + seg * 8] = u;
    }
    if (t < 192) {
      int row = t >> 2, seg = t & 3;
      uint4 v = *(const uint4*)(WT + (size_t)row * K + kc + seg * 8);
      *(uint4*)&Bs[row * 40 + seg * 8] = v;
    }
    __syncthreads();
    bf16x8 af[4], bfr[3];
#pragma unroll
    for (int i = 0; i < 4; ++i)
      af[i] = *(const bf16x8*)&As[(mw + 16 * i + lr) * 40 + lq * 8];
#pragma unroll
    for (int j = 0; j < 3; ++j)
      bfr[j] = *(const bf16x8*)&Bs[(16 * j + lr) * 40 + lq * 8];
#pragma unroll
    for (int i = 0; i < 4; ++i)
#pragma unroll
      for (int j = 0; j < 3; ++j)
        acc[i][j] = __builtin_amdgcn_mfma_f32_16x16x32_bf16(af[i], bfr[j], acc[i][j], 0, 0, 0);
  }

  if (SOFTMAX) {
    float bv0 = bf2f((unsigned)bias[lr]);
    float bv1 = bf2f((unsigned)bias[16 + lr]);
    float bv2 = (lr < 8) ? bf2f((unsigned)bias[32 + lr]) : 0.f;
#pragma unroll
    for (int i = 0; i < 4; ++i) {
#pragma unroll
      for (int r = 0; r < 4; ++r) {
        int row = m0 + mw + 16 * i + lq * 4 + r;
        float v0 = acc[i][0][r] + bv0;
        float v1 = acc[i][1][r] + bv1;
        float v2 = (lr < 8) ? (acc[i][2][r] + bv2) : -1e30f;
        float m = fmaxf(fmaxf(v0, v1), v2);
#pragma unroll
        for (int o = 8; o > 0; o >>= 1) m = fmaxf(m, __shfl_xor(m, o, 16));
        float ss = expf(v0 - m) + expf(v1 - m) + ((lr < 8) ? expf(v2 - m) : 0.f);
#pragma unroll
        for (int o = 8; o > 0; o >>= 1) ss += __shfl_xor(ss, o, 16);
        float ls = logf(ss) + m;
        if (row < NNODES) {
          outp[(size_t)row * 160 + lr] = v0 - ls;
          outp[(size_t)row * 160 + 16 + lr] = v1 - ls;
          if (lr < 8) outp[(size_t)row * 160 + 32 + lr] = v2 - ls;
        }
      }
    }
  } else {
#pragma unroll
    for (int i = 0; i < 4; ++i) {
#pragma unroll
      for (int r = 0; r < 4; ++r) {
        int row = m0 + mw + 16 * i + lq * 4 + r;
        if (row < NNODES) {
          Pout[(size_t)row * 40 + lr] = f2bf(acc[i][0][r]);
          Pout[(size_t)row * 40 + 16 + lr] = f2bf(acc[i][1][r]);
          if (lr < 8) Pout[(size_t)row * 40 + 32 + lr] = f2bf(acc[i][2][r]);
        }
      }
    }
  }
}

// ---------- launch ----------
extern "C" void kernel_launch(void* const* d_in, const int* in_sizes, int n_in,
                              void* d_out, int out_size, void* d_ws, size_t ws_size,
                              hipStream_t stream) {
  const void* x_raw   = d_in[0];
  const int* ei       = (const int*)d_in[1];
  float* out          = (float*)d_out;

  char* ws = (char*)d_ws;
  int*   flags    = (int*)(ws + 0);
  int*   bsum     = (int*)(ws + 1024);
  int*   bbase    = (int*)(ws + 2816);
  int*   cnt      = (int*)(ws + 8192);
  int*   offs     = (int*)(ws + 524288);
  int*   cursor   = (int*)(ws + 1048576);
  float* dinv     = (float*)(ws + 1572864);
  uint2* csr_sc   = (uint2*)(ws + 2097152);     // 12.8 MB {src,coef}
  unsigned short* xb = (unsigned short*)(ws + 16777216);   // N*128 bf16 (reused as P)
  unsigned short* wb = (unsigned short*)(ws + 45088768);   // weights
  unsigned short* hA = (unsigned short*)(ws + 48234496);   // N*256 bf16
  unsigned short* hB = (unsigned short*)(ws + 100663296);  // N*256 bf16
  unsigned short* P  = xb;

  unsigned short* Wc0 = wb + 0;
  unsigned short* bc0 = wb + 32768;
  unsigned short* Wc1 = wb + 33024;
  unsigned short* bc1 = wb + 98560;
  unsigned short* We0 = wb + 98816;
  unsigned short* be0 = wb + 103936;
  unsigned short* We1 = wb + 103976;
  unsigned short* be1 = wb + 109096;
  unsigned short* We2 = wb + 109136;
  unsigned short* be2 = wb + 119376;
  unsigned short* We3 = wb + 119416;
  unsigned short* be3 = wb + 129656;
  unsigned short* WTc0  = wb + 131072;  // 256 x 128
  unsigned short* WTc1  = wb + 163840;  // 256 x 256
  unsigned short* WT40e0 = wb + 229376; // 48 x 128
  unsigned short* WT40e1 = wb + 235520; // 48 x 128
  unsigned short* WT40e2 = wb + 241664; // 48 x 256
  unsigned short* WT40e3 = wb + 253952; // 48 x 256

  dim3 B(256);
  k_probe<<<dim3(1), B, 0, stream>>>((const unsigned*)x_raw, ei, flags);
  k_zero<<<dim3(391), B, 0, stream>>>(cnt, NNODES);

  CvtParams p;
  const int srcIdx[13] = {0, 2, 3, 4, 5, 8, 9, 10, 11, 12, 13, 14, 15};
  unsigned short* dsts[13] = {xb, Wc0, bc0, Wc1, bc1, We0, be0, We1, be1, We2, be2, We3, be3};
  const int ns[13] = {NNODES * 128, 128 * 256, 256, 256 * 256, 256,
                      128 * 40, 40, 128 * 40, 40, 256 * 40, 40, 256 * 40, 40};
  for (int i = 0; i < 13; ++i) { p.src[i] = d_in[srcIdx[i]]; p.dst[i] = dsts[i]; p.n[i] = ns[i]; }
  k_cvt<<<dim3(1024, 13), B, 0, stream>>>(p, flags);
  k_transpose<<<dim3(128), B, 0, stream>>>(Wc0, WTc0, 128);
  k_transpose<<<dim3(256), B, 0, stream>>>(Wc1, WTc1, 256);
  k_transpose40<128><<<dim3(24), B, 0, stream>>>(We0, WT40e0);
  k_transpose40<128><<<dim3(24), B, 0, stream>>>(We1, WT40e1);
  k_transpose40<256><<<dim3(48), B, 0, stream>>>(We2, WT40e2);
  k_transpose40<256><<<dim3(48), B, 0, stream>>>(We3, WT40e3);

  k_count<<<dim3(6250), B, 0, stream>>>(ei, cnt, flags);
  k_dinv<<<dim3(391), B, 0, stream>>>(cnt, dinv);
  k_psum<<<dim3(391), B, 0, stream>>>(cnt, bsum);
  k_bscan<<<dim3(1), dim3(64), 0, stream>>>(bsum, bbase, offs);
  k_offs<<<dim3(391), B, 0, stream>>>(cnt, bbase, offs, cursor);
  k_fill<<<dim3(6250), B, 0, stream>>>(ei, cursor, csr_sc, dinv, flags);

  // layer 0: on x
  k_exit_mfma<128, true><<<dim3(391), B, 0, stream>>>(xb, WT40e0, be0, out + 0 * 40, nullptr);
  // h1 = agg(x)
  k_agg<128><<<dim3(25000), B, 0, stream>>>(xb, hA, offs, csr_sc, dinv);
  k_exit_mfma<128, true><<<dim3(391), B, 0, stream>>>(hA, WT40e1, be1, out + 1 * 40, nullptr);
  k_mlp_mfma<128><<<dim3(782, 2), B, 0, stream>>>(hA, WTc0, bc0, hB);
  // h2 = agg(relu(h1 Wc0 + bc0))
  k_agg<256><<<dim3(25000), B, 0, stream>>>(hB, hA, offs, csr_sc, dinv);
  k_exit_mfma<256, true><<<dim3(391), B, 0, stream>>>(hA, WT40e2, be2, out + 2 * 40, nullptr);
  k_mlp_mfma<256><<<dim3(782, 2), B, 0, stream>>>(hA, WTc1, bc1, hB);
  // layer 3 push-through: out3 = logsoftmax(agg(hc2 @ We3) + be3)
  k_exit_mfma<256, false><<<dim3(391), B, 0, stream>>>(hB, WT40e3, nullptr, nullptr, P);
  k_agg40<<<dim3(25000), B, 0, stream>>>(P, offs, csr_sc, dinv, be3, out + 3 * 40);
}